// Round 1
// baseline (170.603 us; speedup 1.0000x reference)
//
#include <hip/hip_runtime.h>
#include <hip/hip_bf16.h>

// SioConv: out[b,i,d] = Re(h[i]) where
//   a[b,l,d] = (re,im) * rsqrt(re^2+im^2) * exp(-(re^2+im^2)),  (re,im) = x[b,l,:] @ W_a[2d,:]/W_a[2d+1,:]
//   g[i] = a_i * (x_hat[i] + g[i+1])   (backward scan, g[L]=0)
//   h[i] = g[i] + x_hat[i-1] (i>=1), h[0]=g[0], h[L-1] += x[b,L-1,d]
//   x_hat[0] = h0 (complex), x_hat[k] = x[b,k-1,d] (real)

constexpr int B = 2, L = 256, D = 256, K = 256;
constexpr int LT = 4;  // l-rows per block in the GEMM (W-row reuse factor)

__global__ __launch_bounds__(256) void gemm_a_kernel(
    const float* __restrict__ x,    // [B, L, K]
    const float* __restrict__ W,    // [2D, K]
    float2* __restrict__ a)         // [B, L, D]  (ws)
{
    const int blk = blockIdx.x;           // 0 .. B*(L/LT)-1
    const int b  = blk / (L / LT);
    const int l0 = (blk % (L / LT)) * LT;
    const int d  = threadIdx.x;           // 0..255

    __shared__ float xs[LT][K];           // 4 KB

    // Coalesced stage of LT contiguous rows (LT*K = 1024 floats = 256 float4)
    const float4* src = (const float4*)(x + (size_t)(b * L + l0) * K);
    ((float4*)&xs[0][0])[d] = src[d];
    __syncthreads();

    const float4* w0 = (const float4*)(W + (size_t)(2 * d) * K);
    const float4* w1 = (const float4*)(W + (size_t)(2 * d + 1) * K);

    float accr[LT] = {0.f, 0.f, 0.f, 0.f};
    float acci[LT] = {0.f, 0.f, 0.f, 0.f};

#pragma unroll 4
    for (int k = 0; k < K / 4; ++k) {
        const float4 v0 = w0[k];
        const float4 v1 = w1[k];
#pragma unroll
        for (int r = 0; r < LT; ++r) {
            // same LDS address across all lanes -> broadcast, conflict-free
            const float4 xv = ((const float4*)&xs[r][0])[k];
            accr[r] += v0.x * xv.x + v0.y * xv.y + v0.z * xv.z + v0.w * xv.w;
            acci[r] += v1.x * xv.x + v1.y * xv.y + v1.z * xv.z + v1.w * xv.w;
        }
    }

#pragma unroll
    for (int r = 0; r < LT; ++r) {
        const float re = accr[r], im = acci[r];
        const float m2 = re * re + im * im;
        const float s  = rsqrtf(m2) * expf(-m2);
        // coalesced float2 store: lane d -> consecutive addresses
        a[(size_t)(b * L + l0 + r) * D + d] = make_float2(re * s, im * s);
    }
}

__global__ __launch_bounds__(256) void scan_h_kernel(
    const float* __restrict__ x,    // [B, L, D]
    const float2* __restrict__ a,   // [B, L, D]
    const float* __restrict__ h0r,  // [D]
    const float* __restrict__ h0i,  // [D]
    float* __restrict__ out)        // [B, L, D]
{
    const int t = blockIdx.x * blockDim.x + threadIdx.x;  // 0..B*D-1
    if (t >= B * D) return;
    const int b = t / D;
    const int d = t % D;

    const float2* ap = a   + (size_t)b * L * D + d;
    const float*  xp = x   + (size_t)b * L * D + d;
    float*        op = out + (size_t)b * L * D + d;

    const float hr = h0r[d];
    const float hi = h0i[d];
    const float x_last = xp[(size_t)(L - 1) * D];

    float gr = 0.f, gi = 0.f;
    for (int i = L - 1; i >= 0; --i) {
        const float2 ai = ap[(size_t)i * D];
        float xr, xi;
        if (i == 0) { xr = hr; xi = hi; }
        else        { xr = xp[(size_t)(i - 1) * D]; xi = 0.f; }
        const float tr = xr + gr;
        const float ti = xi + gi;
        gr = ai.x * tr - ai.y * ti;
        gi = ai.x * ti + ai.y * tr;

        float o = gr;
        if (i >= 2)      o += xp[(size_t)(i - 2) * D];  // x_hat[i-1] = x[i-2]
        else if (i == 1) o += hr;                       // Re(x_hat[0]) = Re(h0)
        if (i == L - 1)  o += x_last;                   // h[L-1] += x[L-1]
        op[(size_t)i * D] = o;
    }
}

extern "C" void kernel_launch(void* const* d_in, const int* in_sizes, int n_in,
                              void* d_out, int out_size, void* d_ws, size_t ws_size,
                              hipStream_t stream) {
    const float* x    = (const float*)d_in[0];   // B*L*D
    const float* W_a  = (const float*)d_in[1];   // 2D*D
    const float* h0r  = (const float*)d_in[2];   // D
    const float* h0i  = (const float*)d_in[3];   // D
    float* out = (float*)d_out;
    float2* a  = (float2*)d_ws;                  // B*L*D float2 = 1 MiB

    gemm_a_kernel<<<dim3(B * (L / LT)), dim3(256), 0, stream>>>(x, W_a, a);
    scan_h_kernel<<<dim3((B * D + 255) / 256), dim3(256), 0, stream>>>(x, a, h0r, h0i, out);
}

// Round 2
// 82.523 us; speedup vs baseline: 2.0673x; 2.0673x over previous
//
#include <hip/hip_runtime.h>
#include <hip/hip_bf16.h>

// SioConv: out[b,i,d] = Re(h[i]) where
//   a[b,l,d] = (re,im) * rsqrt(m2) * exp(-m2),  (re,im) = x[b,l,:] @ W_a rows 2d/2d+1, m2=re^2+im^2
//   g[i] = a_i * (x_hat[i] + g[i+1])   (backward scan, g[L]=0)
//   out[i] = Re(g[i]) + Re(x_hat[i-1]) (i>=1), out[L-1] += x[b,L-1,d]
//   x_hat[0] = h0 (complex), x_hat[k] = x[b,k-1,d] (real)
//
// R1: scan parallelized as suffix scan of complex affine maps f_i=(A=a_i, B=a_i*xhat_i),
//     compose (A,B) <- (A_i*A_nb, A_i*B_nb + B_i). One block per (b,d) column,
//     thread i owns position i, 8 Hillis-Steele steps through LDS.
//     Previous serial version: 8 waves total -> 98us of raw memory latency.

constexpr int B = 2, L = 256, D = 256, K = 256;
constexpr int LT = 4;  // l-rows per block in the GEMM (W-row reuse factor)

__global__ __launch_bounds__(256) void gemm_a_kernel(
    const float* __restrict__ x,    // [B, L, K]
    const float* __restrict__ W,    // [2D, K]
    float2* __restrict__ a)         // [B, L, D]  (ws)
{
    const int blk = blockIdx.x;           // 0 .. B*(L/LT)-1
    const int b  = blk / (L / LT);
    const int l0 = (blk % (L / LT)) * LT;
    const int d  = threadIdx.x;           // 0..255

    __shared__ float xs[LT][K];           // 4 KB

    const float4* src = (const float4*)(x + (size_t)(b * L + l0) * K);
    ((float4*)&xs[0][0])[d] = src[d];
    __syncthreads();

    const float4* w0 = (const float4*)(W + (size_t)(2 * d) * K);
    const float4* w1 = (const float4*)(W + (size_t)(2 * d + 1) * K);

    float accr[LT] = {0.f, 0.f, 0.f, 0.f};
    float acci[LT] = {0.f, 0.f, 0.f, 0.f};

#pragma unroll 4
    for (int k = 0; k < K / 4; ++k) {
        const float4 v0 = w0[k];
        const float4 v1 = w1[k];
#pragma unroll
        for (int r = 0; r < LT; ++r) {
            const float4 xv = ((const float4*)&xs[r][0])[k];  // LDS broadcast
            accr[r] += v0.x * xv.x + v0.y * xv.y + v0.z * xv.z + v0.w * xv.w;
            acci[r] += v1.x * xv.x + v1.y * xv.y + v1.z * xv.z + v1.w * xv.w;
        }
    }

#pragma unroll
    for (int r = 0; r < LT; ++r) {
        const float re = accr[r], im = acci[r];
        const float m2 = re * re + im * im;
        const float s  = rsqrtf(m2) * expf(-m2);
        a[(size_t)(b * L + l0 + r) * D + d] = make_float2(re * s, im * s);
    }
}

// One block per (b,d) column; thread i owns scan position i.
__global__ __launch_bounds__(256) void scan_h_kernel(
    const float* __restrict__ x,    // [B, L, D]
    const float2* __restrict__ a,   // [B, L, D]
    const float* __restrict__ h0r,  // [D]
    const float* __restrict__ h0i,  // [D]
    float* __restrict__ out)        // [B, L, D]
{
    const int b = blockIdx.x >> 8;
    const int d = blockIdx.x & 255;
    const int i = threadIdx.x;            // position in L

    __shared__ float2 As[L];              // 2 KB
    __shared__ float2 Bs[L];              // 2 KB

    const size_t col = (size_t)b * L * D + d;

    // f_i = (A = a_i, B = a_i * xhat_i)
    const float2 ai = a[col + (size_t)i * D];
    float xr, xi;
    if (i == 0) { xr = h0r[d]; xi = h0i[d]; }
    else        { xr = x[col + (size_t)(i - 1) * D]; xi = 0.f; }

    float Ar = ai.x, Ai = ai.y;
    float Br = ai.x * xr - ai.y * xi;
    float Bi = ai.x * xi + ai.y * xr;

    // Suffix scan: after steps o=1..128, (Ar..Bi) = f_i o f_{i+1} o ... o f_{L-1}
#pragma unroll
    for (int o = 1; o < L; o <<= 1) {
        As[i] = make_float2(Ar, Ai);
        Bs[i] = make_float2(Br, Bi);
        __syncthreads();
        if (i + o < L) {
            const float2 An = As[i + o];
            const float2 Bn = Bs[i + o];
            // new = f_self o f_nb : A = A_self*A_nb ; B = A_self*B_nb + B_self
            const float nAr = Ar * An.x - Ai * An.y;
            const float nAi = Ar * An.y + Ai * An.x;
            const float nBr = Ar * Bn.x - Ai * Bn.y + Br;
            const float nBi = Ar * Bn.y + Ai * Bn.x + Bi;
            Ar = nAr; Ai = nAi; Br = nBr; Bi = nBi;
        }
        __syncthreads();
    }

    // g[i] = B_i (since g[L] = 0). Output epilogue.
    float o_val = Br;
    if (i >= 2)      o_val += x[col + (size_t)(i - 2) * D];  // Re(xhat[i-1]) = x[i-2]
    else if (i == 1) o_val += h0r[d];                        // Re(xhat[0]) = Re(h0)
    if (i == L - 1)  o_val += x[col + (size_t)(L - 1) * D];  // h[L-1] += x[L-1]
    out[col + (size_t)i * D] = o_val;
}

extern "C" void kernel_launch(void* const* d_in, const int* in_sizes, int n_in,
                              void* d_out, int out_size, void* d_ws, size_t ws_size,
                              hipStream_t stream) {
    const float* x    = (const float*)d_in[0];   // B*L*D
    const float* W_a  = (const float*)d_in[1];   // 2D*D
    const float* h0r  = (const float*)d_in[2];   // D
    const float* h0i  = (const float*)d_in[3];   // D
    float* out = (float*)d_out;
    float2* a  = (float2*)d_ws;                  // B*L*D float2 = 1 MiB

    gemm_a_kernel<<<dim3(B * (L / LT)), dim3(256), 0, stream>>>(x, W_a, a);
    scan_h_kernel<<<dim3(B * D), dim3(256), 0, stream>>>(x, a, h0r, h0i, out);
}

// Round 3
// 71.866 us; speedup vs baseline: 2.3739x; 1.1483x over previous
//
#include <hip/hip_runtime.h>
#include <hip/hip_bf16.h>

// SioConv: out[b,i,d] = Re(h[i]) where
//   a[b,l,d] = (re,im) * rsqrt(m2) * exp(-m2),  (re,im) = x[b,l,:] @ W_a rows 2d/2d+1, m2=re^2+im^2
//   g[i] = a_i * (x_hat[i] + g[i+1])   (backward scan, g[L]=0)
//   out[i] = Re(g[i]) + Re(x_hat[i-1]) (i>=1), out[L-1] += x[b,L-1,d]
//   x_hat[0] = h0 (complex), x_hat[k] = x[b,k-1,d] (real)
//
// R2: gemm rewritten as LDS-tiled GEMM. Old version streamed per-thread W rows
//     (lane d -> row 2d, 2 KB apart) -> every load = 64 L2 transactions, 128
//     blocks only -> ~72 us. New: 512 blocks, coalesced float4 staging of a
//     16-l x-tile and 32-row W-tile into LDS (stride 260 = padding to spread
//     banks), compute from LDS b128 reads. Scan unchanged (R1 suffix-scan).

constexpr int B = 2, L = 256, D = 256, K = 256;
constexpr int TL = 16;        // l-rows per block
constexpr int TD = 16;        // d-outputs per block (= 32 W rows)
constexpr int PAD = 260;      // LDS row stride in floats (16B-aligned, breaks bank collide)

__global__ __launch_bounds__(256) void gemm_a_kernel(
    const float* __restrict__ x,    // [B, L, K]
    const float* __restrict__ W,    // [2D, K]
    float2* __restrict__ a)         // [B, L, D]  (ws)
{
    const int dt = blockIdx.x;            // 0..15
    const int lt = blockIdx.y;            // 0..15
    const int b  = blockIdx.z;            // 0..1
    const int t  = threadIdx.x;           // 0..255
    const int l0 = lt * TL;
    const int d0 = dt * TD;
    const int r0 = 2 * d0;                // first W row

    __shared__ float xs[TL][PAD];         // 16.25 KB
    __shared__ float ws[2 * TD][PAD];     // 32.5 KB

    // Stage x rows l0..l0+15 (contiguous 16 KB): 1024 float4, 4 per thread.
    {
        const float4* src = (const float4*)(x + (size_t)(b * L + l0) * K);
#pragma unroll
        for (int j = 0; j < 4; ++j) {
            const int g = j * 256 + t;          // float4 index
            const int row = g >> 6, c4 = g & 63;
            *(float4*)&xs[row][c4 * 4] = src[g];
        }
    }
    // Stage W rows r0..r0+31 (contiguous 32 KB): 2048 float4, 8 per thread.
    {
        const float4* src = (const float4*)(W + (size_t)r0 * K);
#pragma unroll
        for (int j = 0; j < 8; ++j) {
            const int g = j * 256 + t;
            const int row = g >> 6, c4 = g & 63;
            *(float4*)&ws[row][c4 * 4] = src[g];
        }
    }
    __syncthreads();

    const int l  = t >> 4;                // 0..15
    const int dd = t & 15;                // 0..15

    float re = 0.f, im = 0.f;
#pragma unroll 8
    for (int k4 = 0; k4 < K / 4; ++k4) {
        const float4 xv = *(const float4*)&xs[l][k4 * 4];
        const float4 w0 = *(const float4*)&ws[2 * dd][k4 * 4];
        const float4 w1 = *(const float4*)&ws[2 * dd + 1][k4 * 4];
        re += xv.x * w0.x + xv.y * w0.y + xv.z * w0.z + xv.w * w0.w;
        im += xv.x * w1.x + xv.y * w1.y + xv.z * w1.z + xv.w * w1.w;
    }

    const float m2 = re * re + im * im;
    const float s  = rsqrtf(m2) * expf(-m2);
    // lanes: consecutive dd -> consecutive float2 addresses (coalesced)
    a[(size_t)(b * L + l0 + l) * D + d0 + dd] = make_float2(re * s, im * s);
}

// One block per (b,d) column; thread i owns scan position i.
// Suffix scan of complex affine maps f_i = (A=a_i, B=a_i*xhat_i).
__global__ __launch_bounds__(256) void scan_h_kernel(
    const float* __restrict__ x,    // [B, L, D]
    const float2* __restrict__ a,   // [B, L, D]
    const float* __restrict__ h0r,  // [D]
    const float* __restrict__ h0i,  // [D]
    float* __restrict__ out)        // [B, L, D]
{
    const int b = blockIdx.x >> 8;
    const int d = blockIdx.x & 255;
    const int i = threadIdx.x;            // position in L

    __shared__ float2 As[L];              // 2 KB
    __shared__ float2 Bs[L];              // 2 KB

    const size_t col = (size_t)b * L * D + d;

    const float2 ai = a[col + (size_t)i * D];
    float xr, xi;
    if (i == 0) { xr = h0r[d]; xi = h0i[d]; }
    else        { xr = x[col + (size_t)(i - 1) * D]; xi = 0.f; }

    float Ar = ai.x, Ai = ai.y;
    float Br = ai.x * xr - ai.y * xi;
    float Bi = ai.x * xi + ai.y * xr;

#pragma unroll
    for (int o = 1; o < L; o <<= 1) {
        As[i] = make_float2(Ar, Ai);
        Bs[i] = make_float2(Br, Bi);
        __syncthreads();
        if (i + o < L) {
            const float2 An = As[i + o];
            const float2 Bn = Bs[i + o];
            const float nAr = Ar * An.x - Ai * An.y;
            const float nAi = Ar * An.y + Ai * An.x;
            const float nBr = Ar * Bn.x - Ai * Bn.y + Br;
            const float nBi = Ar * Bn.y + Ai * Bn.x + Bi;
            Ar = nAr; Ai = nAi; Br = nBr; Bi = nBi;
        }
        __syncthreads();
    }

    // g[i] = B_i. Output epilogue.
    float o_val = Br;
    if (i >= 2)      o_val += x[col + (size_t)(i - 2) * D];  // Re(xhat[i-1]) = x[i-2]
    else if (i == 1) o_val += h0r[d];                        // Re(xhat[0]) = Re(h0)
    if (i == L - 1)  o_val += x[col + (size_t)(L - 1) * D];  // h[L-1] += x[L-1]
    out[col + (size_t)i * D] = o_val;
}

extern "C" void kernel_launch(void* const* d_in, const int* in_sizes, int n_in,
                              void* d_out, int out_size, void* d_ws, size_t ws_size,
                              hipStream_t stream) {
    const float* x    = (const float*)d_in[0];   // B*L*D
    const float* W_a  = (const float*)d_in[1];   // 2D*D
    const float* h0r  = (const float*)d_in[2];   // D
    const float* h0i  = (const float*)d_in[3];   // D
    float* out = (float*)d_out;
    float2* a  = (float2*)d_ws;                  // B*L*D float2 = 1 MiB

    gemm_a_kernel<<<dim3(D / TD, L / TL, B), dim3(256), 0, stream>>>(x, W_a, a);
    scan_h_kernel<<<dim3(B * D), dim3(256), 0, stream>>>(x, a, h0r, h0i, out);
}